// Round 2
// baseline (461.685 us; speedup 1.0000x reference)
//
#include <hip/hip_runtime.h>
#include <hip/hip_bf16.h>

// Problem constants: B=4, C_in=C_out=16, n=1024, T=16, Ks=3
// out = softmax_c( cosatt(x) * relu(Gconv(x) + x) ), shape [4,16,1024,16] fp32

__device__ __forceinline__ float fast_rcp(float x) {
  float r;
  asm("v_rcp_f32 %0, %1" : "=v"(r) : "v"(x));
  return r;
}

// ---------------------------------------------------------------------------
// Kernel 1:  M1 = X_tmp @ Lk    ([1024 x 1024] @ [1024 x 3072], fp32)
//   X_tmp[r][i] = x[(r>>4)*16384 + i*16 + (r&15)]   (r = (b*16+c)*16 + t)
// Tiled 64x64, BK=16, 256 threads, 4x4 per thread.
// ---------------------------------------------------------------------------
__global__ __launch_bounds__(256) void gemm_xlk(const float* __restrict__ x,
                                                const float* __restrict__ Lk,
                                                float* __restrict__ M1) {
  __shared__ float As[16][68];  // [kk][row], 68*4B=272B rows keep 16B alignment
  __shared__ float Bs[16][64];
  const int tid = threadIdx.x;
  const int tx = tid & 15, ty = tid >> 4;
  const int n0 = blockIdx.x * 64;
  const int m0 = blockIdx.y * 64;
  const int qbase = m0 >> 4;  // 4 consecutive q's per block
  float acc[4][4] = {};

  for (int k0 = 0; k0 < 1024; k0 += 16) {
    // A tile: 64 rows (4 q x 16 t) x 16 kk.  x rows are exactly 64B lines ->
    // mapping lanes (t fast, i next) gives fully coalesced 256B segments.
#pragma unroll
    for (int rep = 0; rep < 4; ++rep) {
      int e = rep * 256 + tid;      // 0..1023
      int q_l = e >> 8;             // 0..3
      int i_l = (e >> 4) & 15;      // kk
      int t_l = e & 15;
      As[i_l][q_l * 16 + t_l] = x[(qbase + q_l) * 16384 + (k0 + i_l) * 16 + t_l];
    }
#pragma unroll
    for (int rep = 0; rep < 4; ++rep) {
      int e = rep * 256 + tid;
      int kk = e >> 6, col = e & 63;
      Bs[kk][col] = Lk[(size_t)(k0 + kk) * 3072 + n0 + col];
    }
    __syncthreads();
#pragma unroll
    for (int kk = 0; kk < 16; ++kk) {
      float4 av = *(const float4*)&As[kk][ty * 4];
      float4 bv = *(const float4*)&Bs[kk][tx * 4];
      float a[4] = {av.x, av.y, av.z, av.w};
      float bb[4] = {bv.x, bv.y, bv.z, bv.w};
#pragma unroll
      for (int r2 = 0; r2 < 4; ++r2)
#pragma unroll
        for (int c2 = 0; c2 < 4; ++c2) acc[r2][c2] += a[r2] * bb[c2];
    }
    __syncthreads();
  }
#pragma unroll
  for (int r2 = 0; r2 < 4; ++r2) {
    int row = m0 + ty * 4 + r2;
    *(float4*)&M1[(size_t)row * 3072 + n0 + tx * 4] =
        make_float4(acc[r2][0], acc[r2][1], acc[r2][2], acc[r2][3]);
  }
}

// ---------------------------------------------------------------------------
// Kernel 2: fused cosine attention + theta contraction + relu fuse.
// One thread per (b,c,i) row. x[b,c] staged in LDS in two 512-row halves.
// Writes pre-softmax logits directly into d_out (layout [b,c,i,t]).
// ---------------------------------------------------------------------------
__global__ __launch_bounds__(256) void attn_fuse(const float* __restrict__ x,
                                                 const float* __restrict__ beta,
                                                 const float* __restrict__ theta,
                                                 const float* __restrict__ bias,
                                                 const float* __restrict__ M1,
                                                 float* __restrict__ out) {
  __shared__ float xsh[512 * 16];  // 32 KB (half of x[b,c])
  __shared__ float nsh[512];       // norms of staged rows
  const int tid = threadIdx.x;
  const int bc = blockIdx.x >> 2;     // b*16+c
  const int chunk = blockIdx.x & 3;   // which 256-row slab of i
  const int b = bc >> 4, c = bc & 15;
  const float* xb = x + (size_t)bc * 16384;
  const int i = chunk * 256 + tid;

  // own row + norm (from global, fully coalesced)
  float xi[16];
#pragma unroll
  for (int q = 0; q < 4; ++q) {
    float4 v = ((const float4*)(xb + i * 16))[q];
    xi[q * 4 + 0] = v.x; xi[q * 4 + 1] = v.y; xi[q * 4 + 2] = v.z; xi[q * 4 + 3] = v.w;
  }
  float ss = 0.f;
#pragma unroll
  for (int t = 0; t < 16; ++t) ss += xi[t] * xi[t];
  const float ni = sqrtf(ss);

  float acc[16];
#pragma unroll
  for (int t = 0; t < 16; ++t) acc[t] = 0.f;

  for (int half = 0; half < 2; ++half) {
    __syncthreads();  // everyone done reading previous half
    const float* src = xb + half * 512 * 16;
#pragma unroll
    for (int r = 0; r < 8; ++r) {
      int e = r * 256 + tid;  // float4 index, 2048 total
      ((float4*)xsh)[e] = ((const float4*)src)[e];
    }
    __syncthreads();  // xsh fully staged before cross-thread norm reads (R1 race fix)
#pragma unroll
    for (int r = 0; r < 2; ++r) {
      int jr = r * 256 + tid;
      float s2 = 0.f;
#pragma unroll
      for (int t = 0; t < 16; ++t) { float v = xsh[jr * 16 + t]; s2 += v * v; }
      nsh[jr] = sqrtf(s2);
    }
    __syncthreads();  // nsh ready

    const float* brow = beta + (size_t)i * 1024 + half * 512;
    for (int ip = 0; ip < 512; ip += 4) {
      float4 b4 = *(const float4*)(brow + ip);
      float bArr[4] = {b4.x, b4.y, b4.z, b4.w};
#pragma unroll
      for (int u = 0; u < 4; ++u) {
        int jj = ip + u;
        float xv[16];
#pragma unroll
        for (int q = 0; q < 4; ++q) {          // broadcast ds_read_b128 x4
          float4 v = ((const float4*)(xsh + jj * 16))[q];
          xv[q * 4 + 0] = v.x; xv[q * 4 + 1] = v.y; xv[q * 4 + 2] = v.z; xv[q * 4 + 3] = v.w;
        }
        float dot = 0.f;
#pragma unroll
        for (int t = 0; t < 16; ++t) dot += xi[t] * xv[t];
        float cosv = dot * fast_rcp(ni * nsh[jj] + 1e-7f);
        float z = bArr[u] * cosv;
        float p = fast_rcp(1.f + __expf(-z));  // sigmoid
#pragma unroll
        for (int t = 0; t < 16; ++t) acc[t] += p * xv[t];
      }
    }
  }

  // ---- graph-conv contribution (theta contraction over M1) + fuse ----
  float thc[48];
#pragma unroll
  for (int w = 0; w < 48; ++w) thc[w] = theta[w * 16 + c];  // block-uniform
  const float bsv = bias[c];
  float res[16];
#pragma unroll 2
  for (int t = 0; t < 16; ++t) {
    const float* mp = M1 + (size_t)((b * 16 + t) * 16) * 3072 + i;
    float g = bsv;
#pragma unroll
    for (int tau = 0; tau < 16; ++tau)
#pragma unroll
      for (int k = 0; k < 3; ++k)
        g += mp[tau * 3072 + k * 1024] * thc[tau * 3 + k];  // coalesced over i
    res[t] = acc[t] * fmaxf(g + xi[t], 0.f);
  }
  float* op = out + (size_t)(bc * 1024 + i) * 16;
#pragma unroll
  for (int q = 0; q < 4; ++q)
    ((float4*)op)[q] = make_float4(res[q * 4], res[q * 4 + 1], res[q * 4 + 2], res[q * 4 + 3]);
}

// ---------------------------------------------------------------------------
// Kernel 3: softmax over channel axis (16 values, stride 1024*16), in-place.
// One block per (b,i); 256 threads = (c=16) x (t=16).
// ---------------------------------------------------------------------------
__global__ __launch_bounds__(256) void softmax_c(float* __restrict__ out) {
  const int b = blockIdx.x >> 10;
  const int i = blockIdx.x & 1023;
  const int tid = threadIdx.x;
  const int c = tid >> 4, t = tid & 15;
  __shared__ float sm[16][17];
  __shared__ float es[16][17];
  const size_t idx = ((size_t)(b * 16 + c) * 1024 + i) * 16 + t;
  float v = out[idx];
  sm[c][t] = v;
  __syncthreads();
  float m = -1e30f;
#pragma unroll
  for (int cc = 0; cc < 16; ++cc) m = fmaxf(m, sm[cc][t]);
  float e = __expf(v - m);
  es[c][t] = e;
  __syncthreads();
  float s = 0.f;
#pragma unroll
  for (int cc = 0; cc < 16; ++cc) s += es[cc][t];
  out[idx] = e / s;
}

// ---------------------------------------------------------------------------
extern "C" void kernel_launch(void* const* d_in, const int* in_sizes, int n_in,
                              void* d_out, int out_size, void* d_ws, size_t ws_size,
                              hipStream_t stream) {
  const float* x     = (const float*)d_in[0];  // [4,16,1024,16]
  const float* beta  = (const float*)d_in[1];  // [1,1,1024,1024]
  const float* theta = (const float*)d_in[2];  // [48,16]
  const float* bias  = (const float*)d_in[3];  // [16]
  const float* Lk    = (const float*)d_in[4];  // [1024,3072]
  float* out = (float*)d_out;
  float* M1 = (float*)d_ws;                    // 1024*3072 fp32 = 12 MB scratch

  dim3 gg(48, 16);  // N-tiles x M-tiles
  gemm_xlk<<<gg, 256, 0, stream>>>(x, Lk, M1);
  attn_fuse<<<256, 256, 0, stream>>>(x, beta, theta, bias, M1, out);
  softmax_c<<<4096, 256, 0, stream>>>(out);
}

// Round 3
// 232.247 us; speedup vs baseline: 1.9879x; 1.9879x over previous
//
#include <hip/hip_runtime.h>
#include <hip/hip_bf16.h>

// B=4, C=16, n=1024, T=16, Ks=3
// out = softmax_c( cosatt(x) * relu(Gconv(x) + x) ), [4,16,1024,16] fp32

using short8v = __attribute__((ext_vector_type(8))) short;
using float4v = __attribute__((ext_vector_type(4))) float;

__device__ __forceinline__ float fast_rcp(float x) {
  float r;
  asm("v_rcp_f32 %0, %1" : "=v"(r) : "v"(x));
  return r;
}
__device__ __forceinline__ unsigned short f2bf(float f) {
  union { float f; unsigned u; } v; v.f = f;
  unsigned r = v.u + 0x7FFF + ((v.u >> 16) & 1);  // RNE
  return (unsigned short)(r >> 16);
}
__device__ __forceinline__ float bf2f(unsigned short h) {
  union { unsigned u; float f; } v; v.u = (unsigned)h << 16;
  return v.f;
}

// ---------------------------------------------------------------------------
// Kernel 1:  M1 = X_tmp @ Lk  ([1024x1024]@[1024x3072]) via split-bf16 MFMA.
//   X_tmp[r][i] = x[(r>>4)*16384 + i*16 + (r&15)]
// A = Ah+Al, B = Bh+Bl; C ~= Ah*Bh + Al*Bh + Ah*Bl  (Al*Bl ~2^-18 rel, dropped)
// Block: 256 thr (4 waves, 2x2), tile 128x128, K-step 32.
// LDS layout is fragment-linear: chunk (f, g, r) holds 8 bf16 of
// row/col (f*16+r), k = g*8..g*8+7, at chunk index f*64 + g*16 + r, so a
// wave's frag read (lane l -> chunk f*64 + l) is a contiguous, conflict-free
// 1KB ds_read_b128.
// ---------------------------------------------------------------------------
__global__ __launch_bounds__(256) void gemm_mfma(const float* __restrict__ x,
                                                 const float* __restrict__ Lk,
                                                 float* __restrict__ M1) {
  __shared__ unsigned short Ah[512 * 8], Al[512 * 8];  // 8 KB each
  __shared__ unsigned short Bh[512 * 8], Bl[512 * 8];
  const int tid = threadIdx.x;
  const int lane = tid & 63, w = tid >> 6;
  const int wm = w >> 1, wn = w & 1;
  const int n0 = blockIdx.x * 128, m0 = blockIdx.y * 128;
  const int qbase = m0 >> 4;
  float4v acc[4][4] = {};

  for (int k0 = 0; k0 < 1024; k0 += 32) {
    __syncthreads();  // previous tiles fully consumed
#pragma unroll
    for (int rep = 0; rep < 2; ++rep) {
      int ch = rep * 256 + tid;           // 0..511
      int f = ch >> 6, g = (ch >> 4) & 3, r = ch & 15;
      // ---- A chunk: rows of X_tmp (gathered from x) ----
      const float* pa = x + (size_t)(qbase + f) * 16384 + (size_t)(k0 + g * 8) * 16 + r;
      short8v hv, lv;
#pragma unroll
      for (int j = 0; j < 8; ++j) {
        float v = pa[j * 16];
        unsigned short h = f2bf(v);
        hv[j] = (short)h;
        lv[j] = (short)f2bf(v - bf2f(h));
      }
      ((short8v*)Ah)[ch] = hv;
      ((short8v*)Al)[ch] = lv;
      // ---- B chunk: Lk columns ----
      const float* pb = Lk + (size_t)(k0 + g * 8) * 3072 + n0 + f * 16 + r;
#pragma unroll
      for (int j = 0; j < 8; ++j) {
        float v = pb[(size_t)j * 3072];
        unsigned short h = f2bf(v);
        hv[j] = (short)h;
        lv[j] = (short)f2bf(v - bf2f(h));
      }
      ((short8v*)Bh)[ch] = hv;
      ((short8v*)Bl)[ch] = lv;
    }
    __syncthreads();

    short8v a_h[4], a_l[4], b_h[4], b_l[4];
#pragma unroll
    for (int f = 0; f < 4; ++f) {
      a_h[f] = ((const short8v*)Ah)[(wm * 4 + f) * 64 + lane];
      a_l[f] = ((const short8v*)Al)[(wm * 4 + f) * 64 + lane];
      b_h[f] = ((const short8v*)Bh)[(wn * 4 + f) * 64 + lane];
      b_l[f] = ((const short8v*)Bl)[(wn * 4 + f) * 64 + lane];
    }
#pragma unroll
    for (int fm = 0; fm < 4; ++fm)
#pragma unroll
      for (int fn = 0; fn < 4; ++fn) {
        acc[fm][fn] = __builtin_amdgcn_mfma_f32_16x16x32_bf16(a_h[fm], b_h[fn], acc[fm][fn], 0, 0, 0);
        acc[fm][fn] = __builtin_amdgcn_mfma_f32_16x16x32_bf16(a_l[fm], b_h[fn], acc[fm][fn], 0, 0, 0);
        acc[fm][fn] = __builtin_amdgcn_mfma_f32_16x16x32_bf16(a_h[fm], b_l[fn], acc[fm][fn], 0, 0, 0);
      }
  }

  // C/D layout (m89-verified): col = lane&15, row = (lane>>4)*4 + reg
#pragma unroll
  for (int fm = 0; fm < 4; ++fm)
#pragma unroll
    for (int fn = 0; fn < 4; ++fn) {
      int col = n0 + wn * 64 + fn * 16 + (lane & 15);
      int rowb = m0 + wm * 64 + fm * 16 + (lane >> 4) * 4;
#pragma unroll
      for (int reg = 0; reg < 4; ++reg)
        M1[(size_t)(rowb + reg) * 3072 + col] = acc[fm][fn][reg];
    }
}

// ---------------------------------------------------------------------------
// Kernel 2: fused cosine attention + theta contraction + relu fuse.
// 512 blocks (64 bc x 8 i-slabs of 128), 512 threads: il = tid&127 (row),
// jq = tid>>7 (4-way j split). j staged in 4 chunks of 256 rows.
// ---------------------------------------------------------------------------
__global__ __launch_bounds__(512) void attn_fuse(const float* __restrict__ x,
                                                 const float* __restrict__ beta,
                                                 const float* __restrict__ theta,
                                                 const float* __restrict__ bias,
                                                 const float* __restrict__ M1,
                                                 float* __restrict__ out) {
  __shared__ float xsh[256 * 16];       // 16 KB (current j-chunk)
  __shared__ float nsh[256];            // 1 KB
  __shared__ float accsh[3 * 128 * 16]; // 24 KB (partial-acc combine)
  const int tid = threadIdx.x;
  const int il = tid & 127, jq = tid >> 7;
  const int bc = blockIdx.x >> 3, slab = blockIdx.x & 7;
  const int b = bc >> 4, c = bc & 15;
  const float* xb = x + (size_t)bc * 16384;
  const int i = slab * 128 + il;

  // own row + norm
  float xi[16];
#pragma unroll
  for (int q = 0; q < 4; ++q) {
    float4 v = ((const float4*)(xb + i * 16))[q];
    xi[q * 4 + 0] = v.x; xi[q * 4 + 1] = v.y; xi[q * 4 + 2] = v.z; xi[q * 4 + 3] = v.w;
  }
  float ss = 0.f;
#pragma unroll
  for (int t = 0; t < 16; ++t) ss += xi[t] * xi[t];
  const float ni = sqrtf(ss);

  float acc[16];
#pragma unroll
  for (int t = 0; t < 16; ++t) acc[t] = 0.f;

  for (int chk = 0; chk < 4; ++chk) {
    __syncthreads();  // previous chunk fully consumed
    const float* src = xb + chk * 256 * 16;
#pragma unroll
    for (int r = 0; r < 2; ++r)
      ((float4*)xsh)[r * 512 + tid] = ((const float4*)src)[r * 512 + tid];
    __syncthreads();  // staged before cross-thread norm reads
    if (tid < 256) {
      float s2 = 0.f;
#pragma unroll
      for (int t = 0; t < 16; ++t) { float v = xsh[tid * 16 + t]; s2 += v * v; }
      nsh[tid] = sqrtf(s2);
    }
    __syncthreads();  // norms ready

    const float* brow = beta + (size_t)i * 1024 + chk * 256 + jq * 64;
    for (int jp = 0; jp < 64; jp += 4) {
      float4 b4 = *(const float4*)(brow + jp);
      float bArr[4] = {b4.x, b4.y, b4.z, b4.w};
#pragma unroll
      for (int u = 0; u < 4; ++u) {
        int jj = jq * 64 + jp + u;
        float xv[16];
#pragma unroll
        for (int q = 0; q < 4; ++q) {
          float4 v = ((const float4*)(xsh + jj * 16))[q];
          xv[q * 4 + 0] = v.x; xv[q * 4 + 1] = v.y; xv[q * 4 + 2] = v.z; xv[q * 4 + 3] = v.w;
        }
        float dot = 0.f;
#pragma unroll
        for (int t = 0; t < 16; ++t) dot += xi[t] * xv[t];
        float cosv = dot * fast_rcp(ni * nsh[jj] + 1e-7f);
        float z = bArr[u] * cosv;
        float p = fast_rcp(1.f + __expf(-z));
#pragma unroll
        for (int t = 0; t < 16; ++t) acc[t] += p * xv[t];
      }
    }
  }

  // combine 4 partials per row
  __syncthreads();
  if (jq != 0) {
#pragma unroll
    for (int t = 0; t < 16; ++t) accsh[((jq - 1) * 128 + il) * 16 + t] = acc[t];
  }
  __syncthreads();
  if (jq == 0) {
#pragma unroll
    for (int t = 0; t < 16; ++t)
      acc[t] += accsh[il * 16 + t] + accsh[(128 + il) * 16 + t] + accsh[(256 + il) * 16 + t];

    // graph-conv tail + fuse
    float thc[48];
#pragma unroll
    for (int wght = 0; wght < 48; ++wght) thc[wght] = theta[wght * 16 + c];
    const float bsv = bias[c];
    float res[16];
#pragma unroll 2
    for (int t = 0; t < 16; ++t) {
      const float* mp = M1 + (size_t)((b * 16 + t) * 16) * 3072 + i;
      float g = bsv;
#pragma unroll
      for (int tau = 0; tau < 16; ++tau)
#pragma unroll
        for (int k = 0; k < 3; ++k)
          g += mp[tau * 3072 + k * 1024] * thc[tau * 3 + k];
      res[t] = acc[t] * fmaxf(g + xi[t], 0.f);
    }
    float* op = out + (size_t)(bc * 1024 + i) * 16;
#pragma unroll
    for (int q = 0; q < 4; ++q)
      ((float4*)op)[q] = make_float4(res[q * 4], res[q * 4 + 1], res[q * 4 + 2], res[q * 4 + 3]);
  }
}

// ---------------------------------------------------------------------------
// Kernel 3: softmax over channel axis (16 values, stride 1024*16), in-place.
// ---------------------------------------------------------------------------
__global__ __launch_bounds__(256) void softmax_c(float* __restrict__ out) {
  const int b = blockIdx.x >> 10;
  const int i = blockIdx.x & 1023;
  const int tid = threadIdx.x;
  const int c = tid >> 4, t = tid & 15;
  __shared__ float sm[16][17];
  __shared__ float es[16][17];
  const size_t idx = ((size_t)(b * 16 + c) * 1024 + i) * 16 + t;
  float v = out[idx];
  sm[c][t] = v;
  __syncthreads();
  float m = -1e30f;
#pragma unroll
  for (int cc = 0; cc < 16; ++cc) m = fmaxf(m, sm[cc][t]);
  float e = __expf(v - m);
  es[c][t] = e;
  __syncthreads();
  float s = 0.f;
#pragma unroll
  for (int cc = 0; cc < 16; ++cc) s += es[cc][t];
  out[idx] = e / s;
}

// ---------------------------------------------------------------------------
extern "C" void kernel_launch(void* const* d_in, const int* in_sizes, int n_in,
                              void* d_out, int out_size, void* d_ws, size_t ws_size,
                              hipStream_t stream) {
  const float* x     = (const float*)d_in[0];  // [4,16,1024,16]
  const float* beta  = (const float*)d_in[1];  // [1,1,1024,1024]
  const float* theta = (const float*)d_in[2];  // [48,16]
  const float* bias  = (const float*)d_in[3];  // [16]
  const float* Lk    = (const float*)d_in[4];  // [1024,3072]
  float* out = (float*)d_out;
  float* M1 = (float*)d_ws;                    // 12 MB scratch

  dim3 gg(24, 8);  // 3072/128 x 1024/128
  gemm_mfma<<<gg, 256, 0, stream>>>(x, Lk, M1);
  attn_fuse<<<512, 512, 0, stream>>>(x, beta, theta, bias, M1, out);
  softmax_c<<<4096, 256, 0, stream>>>(out);
}

// Round 5
// 189.864 us; speedup vs baseline: 2.4317x; 1.2232x over previous
//
#include <hip/hip_runtime.h>
#include <hip/hip_bf16.h>
#include <stdint.h>

// B=4, C=16, n=1024, T=16, Ks=3
// out = softmax_c( cosatt(x) * relu(Gconv(x) + x) ), [4,16,1024,16] fp32

using short8v = __attribute__((ext_vector_type(8))) short;
using float4v = __attribute__((ext_vector_type(4))) float;

#define MFMA16(a, b, c) __builtin_amdgcn_mfma_f32_16x16x32_bf16(a, b, c, 0, 0, 0)

// ---- workspace layout (bytes) -- total 46,137,344 ----
static constexpr size_t M1_OFF  = 0;          // 1024x3072 f32
static constexpr size_t O_OFF   = 12582912;   // 64x1024x16 f32 (attention out)
static constexpr size_t XSH_OFF = 16777216;   // x-hat S-frag layout hi  (64bc x 64rf x 64lane x 16B)
static constexpr size_t XSL_OFF = 20971520;   //                     lo
static constexpr size_t XTH_OFF = 25165824;   // RAW-x^T PV-frag layout hi (64bc x 32jt x 64lane x 16B)
static constexpr size_t XTL_OFF = 27262976;   //                        lo
static constexpr size_t AGH_OFF = 29360128;   // GEMM A hi (8tm x 32tk x 512ch x 16B)
static constexpr size_t AGL_OFF = 31457280;
static constexpr size_t BGH_OFF = 33554432;   // GEMM B hi (24tn x 32tk x 512ch x 16B)
static constexpr size_t BGL_OFF = 39845888;

__device__ __forceinline__ float fast_rcp(float x) {
  float r; asm("v_rcp_f32 %0, %1" : "=v"(r) : "v"(x)); return r;
}
__device__ __forceinline__ unsigned f2u(float f) { union { float f; unsigned u; } v; v.f = f; return v.u; }
__device__ __forceinline__ float u2f(unsigned u) { union { unsigned u; float f; } v; v.u = u; return v.f; }
__device__ __forceinline__ unsigned short f2bf(float f) {
  unsigned u = f2u(f);
  return (unsigned short)((u + 0x7FFFu + ((u >> 16) & 1u)) >> 16);  // RNE
}
__device__ __forceinline__ float bf2f(unsigned short h) { return u2f(((unsigned)h) << 16); }

typedef const __attribute__((address_space(1))) unsigned int* gas1_t;
typedef __attribute__((address_space(3))) unsigned int* las3_t;
__device__ __forceinline__ void gload16(const void* g, void* l) {
  __builtin_amdgcn_global_load_lds((gas1_t)g, (las3_t)l, 16, 0, 0);
}

// ---------------------------------------------------------------------------
// prep_gemm: split X_tmp and Lk into bf16 hi/lo in fragment-tile-linear order.
// Chunk ch = f*64 + g*16 + r holds 8 elems (row/col = f*16+r, k = g*8..g*8+7)
// so GEMM frag reads are contiguous 1KB per wave.
// ---------------------------------------------------------------------------
__global__ __launch_bounds__(256) void prep_gemm(const float* __restrict__ x,
                                                 const float* __restrict__ Lk,
                                                 void* __restrict__ ws) {
  const int n = blockIdx.x * 256 + threadIdx.x;
  short8v hv, lv;
  if (n < 131072) {  // A chunks: X_tmp[row][k] = x[(row>>4)*16384 + k*16 + (row&15)]
    const int r = n & 15, g = (n >> 4) & 3, f = (n >> 6) & 7, tk = (n >> 9) & 31, tm = n >> 14;
    const float* p = x + (size_t)(tm * 8 + f) * 16384 + (size_t)(tk * 32 + g * 8) * 16 + r;
#pragma unroll
    for (int j = 0; j < 8; ++j) {
      float v = p[j * 16];
      unsigned short h = f2bf(v);
      hv[j] = (short)h; lv[j] = (short)f2bf(v - bf2f(h));
    }
    ((short8v*)((char*)ws + AGH_OFF))[n] = hv;
    ((short8v*)((char*)ws + AGL_OFF))[n] = lv;
  } else {  // B chunks from Lk[k][col]
    const int nb = n - 131072;
    const int r = nb & 15, g = (nb >> 4) & 3, f = (nb >> 6) & 7, tk = (nb >> 9) & 31, tn = nb >> 14;
    const float* p = Lk + (size_t)(tk * 32 + g * 8) * 3072 + tn * 128 + f * 16 + r;
#pragma unroll
    for (int j = 0; j < 8; ++j) {
      float v = p[(size_t)j * 3072];
      unsigned short h = f2bf(v);
      hv[j] = (short)h; lv[j] = (short)f2bf(v - bf2f(h));
    }
    ((short8v*)((char*)ws + BGH_OFF))[nb] = hv;
    ((short8v*)((char*)ws + BGL_OFF))[nb] = lv;
  }
}

// ---------------------------------------------------------------------------
// prep_attn: XS = bf16 hi/lo of x-hat (= x/||x||, S-operand frags, lanes>=32
// zero for K=16 pad); XT = bf16 hi/lo of RAW x transposed (PV B-frags).
// R4 bug fix: reference computes P @ x (raw), NOT P @ x-hat -> xs stays raw,
// normalization lives only in registers for XS.
// ---------------------------------------------------------------------------
__global__ __launch_bounds__(256) void prep_attn(const float* __restrict__ x,
                                                 void* __restrict__ ws) {
  __shared__ float xs[256 * 16];  // RAW x slab, never modified after stage
  const int tid = threadIdx.x;
  const int bc = blockIdx.x >> 2, ss = blockIdx.x & 3;
  const float* xb = x + (size_t)bc * 16384 + (size_t)ss * 4096;
#pragma unroll
  for (int r = 0; r < 4; ++r) ((float4*)xs)[r * 256 + tid] = ((const float4*)xb)[r * 256 + tid];
  __syncthreads();
  // own row (raw) -> registers, normalize in registers only
  float v[16];
#pragma unroll
  for (int q = 0; q < 4; ++q) {
    float4 t4 = ((float4*)xs)[tid * 4 + q];
    v[q * 4] = t4.x; v[q * 4 + 1] = t4.y; v[q * 4 + 2] = t4.z; v[q * 4 + 3] = t4.w;
  }
  float s2 = 0.f;
#pragma unroll
  for (int t = 0; t < 16; ++t) s2 += v[t] * v[t];
  const float rn = fast_rcp(sqrtf(s2));
#pragma unroll
  for (int t = 0; t < 16; ++t) v[t] *= rn;
  // XS chunks for this row (x-hat)
  unsigned short hh[16], ll[16];
#pragma unroll
  for (int t = 0; t < 16; ++t) { hh[t] = f2bf(v[t]); ll[t] = f2bf(v[t] - bf2f(hh[t])); }
  short8v h0, h1, l0, l1, zz;
#pragma unroll
  for (int j = 0; j < 8; ++j) {
    h0[j] = (short)hh[j]; h1[j] = (short)hh[8 + j];
    l0[j] = (short)ll[j]; l1[j] = (short)ll[8 + j]; zz[j] = 0;
  }
  const int rf = ss * 16 + (tid >> 4);
  short8v* XSh = (short8v*)((char*)ws + XSH_OFF);
  short8v* XSl = (short8v*)((char*)ws + XSL_OFF);
  const size_t base = ((size_t)bc * 64 + rf) * 64;
  const int lo = tid & 15;
  XSh[base + lo] = h0;       XSh[base + 16 + lo] = h1;
  XSh[base + 32 + lo] = zz;  XSh[base + 48 + lo] = zz;
  XSl[base + lo] = l0;       XSl[base + 16 + lo] = l1;
  XSl[base + 32 + lo] = zz;  XSl[base + 48 + lo] = zz;
  // XT gather from RAW xs: chunk (jt_l, lane): t = lane&15, j = jt_l*32 + (lane>>4)*8 + jj
  short8v* XTh = (short8v*)((char*)ws + XTH_OFF);
  short8v* XTl = (short8v*)((char*)ws + XTL_OFF);
#pragma unroll
  for (int rep = 0; rep < 2; ++rep) {
    const int idx = rep * 256 + tid;
    const int jt_l = idx >> 6, l = idx & 63;
    const int t = l & 15, jb = jt_l * 32 + ((l >> 4) << 3);
    short8v ph, pl;
#pragma unroll
    for (int jj = 0; jj < 8; ++jj) {
      float xv = xs[(jb + jj) * 16 + t];
      unsigned short h = f2bf(xv);
      ph[jj] = (short)h; pl[jj] = (short)f2bf(xv - bf2f(h));
    }
    const size_t ci = ((size_t)bc * 32 + ss * 8 + jt_l) * 64 + l;
    XTh[ci] = ph; XTl[ci] = pl;
  }
}

// ---------------------------------------------------------------------------
// gemm_mfma: M1 = X_tmp @ Lk via split-bf16 (AhBh + AlBh + AhBl).
// 128x128 tile, 512 thr (8 waves 2x4), BK=32, double-buffered global_load_lds.
// ---------------------------------------------------------------------------
__global__ __launch_bounds__(512) void gemm_mfma(void* __restrict__ ws) {
  __shared__ unsigned short AhL[2][4096], AlL[2][4096], BhL[2][4096], BlL[2][4096];
  const int tid = threadIdx.x, lane = tid & 63, w = tid >> 6;
  const int wm = w >> 2, wn = w & 3;
  const int bn = blockIdx.x, bm = blockIdx.y;
  const short8v* Agh = (const short8v*)((char*)ws + AGH_OFF);
  const short8v* Agl = (const short8v*)((char*)ws + AGL_OFF);
  const short8v* Bgh = (const short8v*)((char*)ws + BGH_OFF);
  const short8v* Bgl = (const short8v*)((char*)ws + BGL_OFF);
  float* M1 = (float*)((char*)ws + M1_OFF);
  float4v acc[4][2] = {};

  auto stage = [&](int tk, int bb) {
    gload16(&Agh[(size_t)(bm * 32 + tk) * 512 + tid], &AhL[bb][tid * 8]);
    gload16(&Agl[(size_t)(bm * 32 + tk) * 512 + tid], &AlL[bb][tid * 8]);
    gload16(&Bgh[(size_t)(bn * 32 + tk) * 512 + tid], &BhL[bb][tid * 8]);
    gload16(&Bgl[(size_t)(bn * 32 + tk) * 512 + tid], &BlL[bb][tid * 8]);
  };
  stage(0, 0);
  __syncthreads();
  for (int tk = 0; tk < 32; ++tk) {
    const int bb = tk & 1;
    if (tk < 31) stage(tk + 1, bb ^ 1);
    short8v ah[4], al[4], bh[2], bl[2];
#pragma unroll
    for (int fm = 0; fm < 4; ++fm) {
      ah[fm] = *(const short8v*)&AhL[bb][((wm * 4 + fm) * 64 + lane) * 8];
      al[fm] = *(const short8v*)&AlL[bb][((wm * 4 + fm) * 64 + lane) * 8];
    }
#pragma unroll
    for (int fn = 0; fn < 2; ++fn) {
      bh[fn] = *(const short8v*)&BhL[bb][((wn * 2 + fn) * 64 + lane) * 8];
      bl[fn] = *(const short8v*)&BlL[bb][((wn * 2 + fn) * 64 + lane) * 8];
    }
#pragma unroll
    for (int fm = 0; fm < 4; ++fm)
#pragma unroll
      for (int fn = 0; fn < 2; ++fn) {
        acc[fm][fn] = MFMA16(ah[fm], bh[fn], acc[fm][fn]);
        acc[fm][fn] = MFMA16(al[fm], bh[fn], acc[fm][fn]);
        acc[fm][fn] = MFMA16(ah[fm], bl[fn], acc[fm][fn]);
      }
    __syncthreads();
  }
  // C/D: col = lane&15, row = (lane>>4)*4 + reg  (R2-verified)
#pragma unroll
  for (int fm = 0; fm < 4; ++fm)
#pragma unroll
    for (int fn = 0; fn < 2; ++fn) {
      const int col = bn * 128 + (wn * 2 + fn) * 16 + (lane & 15);
      const int rowb = bm * 128 + (wm * 4 + fm) * 16 + ((lane >> 4) << 2);
#pragma unroll
      for (int r = 0; r < 4; ++r) M1[(size_t)(rowb + r) * 3072 + col] = acc[fm][fn][r];
    }
}

// ---------------------------------------------------------------------------
// attn_mfma: flash-style cos-attention, all matmuls on MFMA (split bf16).
// Block = (bc, 128-row i-slab), 256 thr / 4 waves; wave owns 2 i-frags.
// j in 8 tiles of 128 (double-buffered gload16). S = x-hat . x-hat (MFMA),
// sigmoid(beta*cos) in-register, P hi/lo repacked via per-wave LDS, PV = P @
// RAW x (MFMA). Writes O[bc][i][t] f32.
// ---------------------------------------------------------------------------
__global__ __launch_bounds__(256) void attn_mfma(const float* __restrict__ beta,
                                                 void* __restrict__ ws) {
  __shared__ unsigned short XShL[2][4096], XSlL[2][4096];
  __shared__ unsigned short XThL[2][2048], XTlL[2][2048];
  __shared__ unsigned short Pbuf[4][1024];  // per-wave: Ph [0..511], Pl [512..1023]
  const int tid = threadIdx.x, lane = tid & 63, w = tid >> 6;
  const int bc = blockIdx.x >> 3, slab = blockIdx.x & 7;
  const short8v* XSgh = (const short8v*)((char*)ws + XSH_OFF);
  const short8v* XSgl = (const short8v*)((char*)ws + XSL_OFF);
  const short8v* XTgh = (const short8v*)((char*)ws + XTH_OFF);
  const short8v* XTgl = (const short8v*)((char*)ws + XTL_OFF);
  float* O = (float*)((char*)ws + O_OFF);

  short8v ah[2], al[2];
#pragma unroll
  for (int m = 0; m < 2; ++m) {
    const int ifr = slab * 8 + w * 2 + m;
    ah[m] = XSgh[((size_t)bc * 64 + ifr) * 64 + lane];
    al[m] = XSgl[((size_t)bc * 64 + ifr) * 64 + lane];
  }
  float4v o[2] = {};

  auto stage = [&](int jt, int bb) {
    const short8v* sh = XSgh + (size_t)bc * 4096 + jt * 512;
    const short8v* sl = XSgl + (size_t)bc * 4096 + jt * 512;
    gload16(&sh[tid], &XShL[bb][tid * 8]);
    gload16(&sh[256 + tid], &XShL[bb][(256 + tid) * 8]);
    gload16(&sl[tid], &XSlL[bb][tid * 8]);
    gload16(&sl[256 + tid], &XSlL[bb][(256 + tid) * 8]);
    const short8v* th = XTgh + (size_t)bc * 2048 + jt * 256;
    const short8v* tl = XTgl + (size_t)bc * 2048 + jt * 256;
    gload16(&th[tid], &XThL[bb][tid * 8]);
    gload16(&tl[tid], &XTlL[bb][tid * 8]);
  };
  stage(0, 0);
  __syncthreads();

  unsigned short* pb = &Pbuf[w][0];
  for (int jt = 0; jt < 8; ++jt) {
    const int bb = jt & 1;
    if (jt < 7) stage(jt + 1, bb ^ 1);
#pragma unroll
    for (int m = 0; m < 2; ++m) {
      const int ib = slab * 128 + (w * 2 + m) * 16 + ((lane >> 4) << 2);
#pragma unroll
      for (int kk = 0; kk < 4; ++kk) {
#pragma unroll
        for (int fh = 0; fh < 2; ++fh) {
          const int f = kk * 2 + fh;
          short8v bhv = *(const short8v*)&XShL[bb][(f * 64 + lane) * 8];
          short8v blv = *(const short8v*)&XSlL[bb][(f * 64 + lane) * 8];
          float4v s = {0.f, 0.f, 0.f, 0.f};
          s = MFMA16(ah[m], bhv, s);
          s = MFMA16(al[m], bhv, s);
          s = MFMA16(ah[m], blv, s);
          const float* bp = beta + (size_t)ib * 1024 + jt * 128 + f * 16 + (lane & 15);
#pragma unroll
          for (int r = 0; r < 4; ++r) {
            const float z = bp[(size_t)r * 1024] * s[r];   // beta * cos
            const float p = fast_rcp(1.f + __expf(-z));    // sigmoid
            const unsigned short ph = f2bf(p);
            const unsigned short pl = f2bf(p - bf2f(ph));
            const int i = ((lane >> 4) << 2) + r;
            const int jl = fh * 16 + (lane & 15);
            const int sidx = (((jl >> 3) << 4) | i) * 8 + (jl & 7);  // frag-linear
            pb[sidx] = ph;
            pb[512 + sidx] = pl;
          }
        }
        short8v xh = *(const short8v*)&XThL[bb][(kk * 64 + lane) * 8];
        short8v xl = *(const short8v*)&XTlL[bb][(kk * 64 + lane) * 8];
        short8v pha = *(const short8v*)&pb[lane * 8];
        short8v pla = *(const short8v*)&pb[512 + lane * 8];
        o[m] = MFMA16(pha, xh, o[m]);
        o[m] = MFMA16(pla, xh, o[m]);
        o[m] = MFMA16(pha, xl, o[m]);
      }
    }
    __syncthreads();
  }
#pragma unroll
  for (int m = 0; m < 2; ++m)
#pragma unroll
    for (int r = 0; r < 4; ++r) {
      const int ig = slab * 128 + (w * 2 + m) * 16 + ((lane >> 4) << 2) + r;
      O[((size_t)bc * 1024 + ig) * 16 + (lane & 15)] = o[m][r];
    }
}

// ---------------------------------------------------------------------------
// tail_fuse: g = theta-contraction of M1 (LDS-staged slab), logit =
// O * relu(g + x), softmax over c in-register via 16-lane shfl_xor.
// Block = (b, 16-node chunk); 256 thr: c = tid&15, t = tid>>4.
// ---------------------------------------------------------------------------
__global__ __launch_bounds__(256) void tail_fuse(const float* __restrict__ x,
                                                 const float* __restrict__ theta,
                                                 const float* __restrict__ bias,
                                                 const void* __restrict__ ws,
                                                 float* __restrict__ out) {
  __shared__ float m1s[48 * 256];  // [tauk][t][i]
  __shared__ float ths[768];
  const int tid = threadIdx.x;
  const int b = blockIdx.x >> 6, chunk = blockIdx.x & 63, i0 = chunk * 16;
  const float* M1 = (const float*)((const char*)ws + M1_OFF);
  const float* O = (const float*)((const char*)ws + O_OFF);
  {
    const int i = tid & 15, t = tid >> 4;
#pragma unroll
    for (int s = 0; s < 48; ++s)
      m1s[(s * 16 + t) * 16 + i] =
          M1[(size_t)((b * 16 + t) * 16 + s / 3) * 3072 + (s % 3) * 1024 + i0 + i];
  }
#pragma unroll
  for (int r = 0; r < 3; ++r) ths[r * 256 + tid] = theta[r * 256 + tid];
  __syncthreads();
  const int c = tid & 15, t = tid >> 4;
  const int bc = b * 16 + c;
  float xv[16], ov[16];
#pragma unroll
  for (int i = 0; i < 16; ++i) {
    const size_t a = ((size_t)bc * 1024 + i0 + i) * 16 + t;
    xv[i] = x[a]; ov[i] = O[a];
  }
  float thc[48];
#pragma unroll
  for (int s = 0; s < 48; ++s) thc[s] = ths[s * 16 + c];
  float g[16];
  const float bs = bias[c];
#pragma unroll
  for (int i = 0; i < 16; ++i) g[i] = bs;
#pragma unroll
  for (int s = 0; s < 48; ++s) {
    const float4* mp = (const float4*)&m1s[(s * 16 + t) * 16];
    const float th = thc[s];
#pragma unroll
    for (int q = 0; q < 4; ++q) {
      float4 mv = mp[q];
      g[q * 4] += mv.x * th; g[q * 4 + 1] += mv.y * th;
      g[q * 4 + 2] += mv.z * th; g[q * 4 + 3] += mv.w * th;
    }
  }
  float lg[16];
#pragma unroll
  for (int i = 0; i < 16; ++i) lg[i] = ov[i] * fmaxf(g[i] + xv[i], 0.f);
#pragma unroll
  for (int i = 0; i < 16; ++i) {
    float mx = lg[i];
    mx = fmaxf(mx, __shfl_xor(mx, 1)); mx = fmaxf(mx, __shfl_xor(mx, 2));
    mx = fmaxf(mx, __shfl_xor(mx, 4)); mx = fmaxf(mx, __shfl_xor(mx, 8));
    const float e = __expf(lg[i] - mx);
    float sm = e;
    sm += __shfl_xor(sm, 1); sm += __shfl_xor(sm, 2);
    sm += __shfl_xor(sm, 4); sm += __shfl_xor(sm, 8);
    out[((size_t)bc * 1024 + i0 + i) * 16 + t] = e * fast_rcp(sm);
  }
}

// ---------------------------------------------------------------------------
extern "C" void kernel_launch(void* const* d_in, const int* in_sizes, int n_in,
                              void* d_out, int out_size, void* d_ws, size_t ws_size,
                              hipStream_t stream) {
  const float* x     = (const float*)d_in[0];  // [4,16,1024,16]
  const float* beta  = (const float*)d_in[1];  // [1,1,1024,1024]
  const float* theta = (const float*)d_in[2];  // [48,16]
  const float* bias  = (const float*)d_in[3];  // [16]
  const float* Lk    = (const float*)d_in[4];  // [1024,3072]
  float* out = (float*)d_out;

  prep_gemm<<<2048, 256, 0, stream>>>(x, Lk, d_ws);
  prep_attn<<<256, 256, 0, stream>>>(x, d_ws);
  gemm_mfma<<<dim3(24, 8), 512, 0, stream>>>(d_ws);
  attn_mfma<<<512, 256, 0, stream>>>(beta, d_ws);
  tail_fuse<<<256, 256, 0, stream>>>(x, theta, bias, d_ws, out);
}